// Round 1
// baseline (461.977 us; speedup 1.0000x reference)
//
#include <hip/hip_runtime.h>

#define S_MAX 36500.0f
#define S_MIN 0.01f

typedef float vf4 __attribute__((ext_vector_type(4)));

// Two adjacent batch columns per thread (one float4 load + one float4 store
// per step), 16-deep software pipeline in NAMED registers (no arrays -> no
// scratch). Two independent recurrence chains per thread give 2x ILP on the
// serial dependence; 2 waves/CU x 2 chains keeps the same 4-way latency
// hiding as before while halving VMEM events and address math per byte.
// seq_len must be a multiple of 16; batch must be even.
__global__ __launch_bounds__(128) void anki_scan(
    const float* __restrict__ inputs,  // [seq_len][batch][2]
    const float* __restrict__ w,       // [7]
    float* __restrict__ out,           // [seq_len][batch][2] then [batch][2]
    int seq_len, int batch)
{
#pragma clang fp contract(off)
    const int HB   = batch >> 1;                    // column pairs
    const int pair = blockIdx.x * blockDim.x + threadIdx.x;
    if (pair >= HB) return;

    const float w0 = w[0], w1 = w[1], w2 = w[2], w3 = w[3];
    const float w4 = w[4], w5 = w[5], w6 = w[6];

    const vf4* lp = (const vf4*)inputs + pair;      // bumped by HB per step
    vf4*       op = (vf4*)out + pair;               // bumped by HB per step
    vf4*     fin4 = (vf4*)((float2*)out + (size_t)seq_len * batch) + pair;

    float ivl0 = 0.0f, ease0 = 0.0f;
    float ivl1 = 0.0f, ease1 = 0.0f;

    auto upd = [&](float delta_t, float rating, float& ivl, float& ease) {
        const bool is_first = (ivl == 0.0f) || (ease == 0.0f);

        float ne = ease;
        ne = (rating == 1.0f) ? ease - 0.2f  : ne;
        ne = (rating == 2.0f) ? ease - 0.15f : ne;
        ne = (rating == 4.0f) ? ease + 0.15f : ne;
        ne = fminf(fmaxf(ne, 1.3f), 5.5f);

        const float days_late = delta_t - ivl;
        const bool pass_cond  = rating > 1.0f;
        const bool early      = pass_cond && (days_late <  0.0f);
        const bool non_early  = pass_cond && (days_late >= 0.0f);

        const float elapsed = ivl + days_late;
        const float e_hard  = fmaxf(elapsed * w4, ivl * w4 * 0.5f);
        const float e_good  = ivl * ne;
        const float e_easy  = e_good * w3;
        const float ivl_early =
            (rating == 2.0f) ? e_hard : ((rating == 4.0f) ? e_easy : e_good);

        const float n_hard = ivl * w4;
        const float n_good = (ivl + days_late * 0.5f)  * ne;
        const float n_easy = (ivl + days_late * 0.25f) * ne * w3;
        const float ivl_non_early =
            (rating == 2.0f) ? n_hard : ((rating == 4.0f) ? n_easy : n_good);

        const float calc =
            (early ? ivl_early : (non_early ? ivl_non_early : 0.0f)) * w6;

        float new_ivl = pass_cond ? calc : ivl;
        new_ivl = (rating == 1.0f) ? ivl * w5 : new_ivl;
        new_ivl = (is_first && rating <  4.0f) ? w0 : new_ivl;
        new_ivl = (is_first && rating == 4.0f) ? w1 : new_ivl;
        ne      = is_first ? w2 : ne;
        new_ivl = fminf(fmaxf(new_ivl, S_MIN), S_MAX);

        ivl  = new_ivl;
        ease = ne;
    };

    auto step = [&](vf4 x) {
        // Two independent chains -> compiler interleaves the dependent ops.
        upd(x.x, x.y, ivl0, ease0);
        upd(x.z, x.w, ivl1, ease1);
        vf4 o;
        o.x = ivl0; o.y = ease0; o.z = ivl1; o.w = ease1;
        __builtin_nontemporal_store(o, op);   // write-once stream: skip L2 reuse
        op += HB;
    };

#define U16(M) M(0) M(1) M(2) M(3) M(4) M(5) M(6) M(7) \
               M(8) M(9) M(10) M(11) M(12) M(13) M(14) M(15)

    // Prologue: load group 0 into named registers.
#define DECL_C(i) vf4 c##i = __builtin_nontemporal_load(lp); lp += HB;
    U16(DECL_C)
#undef DECL_C

    int t = 0;
    for (; t + 16 < seq_len; t += 16) {
        // Issue all 16 next-group loads up front (in flight during compute).
#define DECL_N(i) vf4 n##i = __builtin_nontemporal_load(lp); lp += HB;
        U16(DECL_N)
#undef DECL_N

        // Compute + store current group (serial recurrence per chain).
#define DO_STEP(i) step(c##i);
        U16(DO_STEP)
#undef DO_STEP

        // Rotate buffers.
#define ROT(i) c##i = n##i;
        U16(ROT)
#undef ROT
    }

    // Epilogue: last group.
#define DO_STEP(i) step(c##i);
    U16(DO_STEP)
#undef DO_STEP
#undef U16

    vf4 f;
    f.x = ivl0; f.y = ease0; f.z = ivl1; f.w = ease1;
    *fin4 = f;
}

extern "C" void kernel_launch(void* const* d_in, const int* in_sizes, int n_in,
                              void* d_out, int out_size, void* d_ws, size_t ws_size,
                              hipStream_t stream) {
    const float* inputs = (const float*)d_in[0];
    const float* w      = (const float*)d_in[1];
    float* out          = (float*)d_out;

    const int seq_len = 512;
    const int batch   = in_sizes[0] / (seq_len * 2);  // 65536

    const int pairs = batch / 2;                      // 32768 threads
    const int block = 128;                            // 256 blocks -> 1 per CU
    const int grid  = (pairs + block - 1) / block;
    anki_scan<<<grid, block, 0, stream>>>(inputs, w, out, seq_len, batch);
}

// Round 2
// 434.039 us; speedup vs baseline: 1.0644x; 1.0644x over previous
//
#include <hip/hip_runtime.h>

#define S_MAX 36500.0f
#define S_MIN 0.01f

typedef float vf4 __attribute__((ext_vector_type(4)));

// One thread per batch column (proven best parallelism split: 65536 threads =
// 1024 waves = 1 wave/SIMD on all 4 SIMDs of all 256 CUs). All global traffic
// goes through LDS block-staging so every HBM access is dwordx4 (1 KB/wave)
// instead of dwordx2 (512 B/wave): halves the request count at the memory
// system for the same bytes.
//
// Block = 128 threads (2 waves) owns 128 adjacent columns. Per 16-step group:
//   - 8 global_load_dwordx4 / thread (group g+1) issued before compute(g)
//   - compute 16 serial steps from in_lds (ds_read_b64), results -> out_lds
//   - barrier; ds_write staged input for g+1; drain out_lds with
//     8 global_store_dwordx4 / thread; barrier.
// seq_len must be a multiple of 16; batch a multiple of 128.
__global__ __launch_bounds__(128) void anki_scan(
    const float* __restrict__ inputs,  // [seq_len][batch][2]
    const float* __restrict__ w,       // [7]
    float* __restrict__ out,           // [seq_len][batch][2] then [batch][2]
    int seq_len, int batch)
{
#pragma clang fp contract(off)
    const int tid  = threadIdx.x;
    const int C0   = blockIdx.x * 128;     // first column owned by this block
    const int col  = C0 + tid;             // this thread's column
    const int B4   = batch >> 1;           // float4s per timestep row
    const int slot = tid & 63;             // position within a step row
    const int srow = tid >> 6;             // 0 or 1: which step of each pair
    const int cbase = (C0 >> 1) + slot;    // float4 index of slot in a row

    // 16 steps x 128 cols x 2 floats = 16 KB each; 32 KB/block, 2 blocks/CU.
    __shared__ __align__(16) float in_lds [16][256];
    __shared__ __align__(16) float out_lds[16][256];

    const float w0 = w[0], w1 = w[1], w2 = w[2], w3 = w[3];
    const float w4 = w[4], w5 = w[5], w6 = w[6];

    const vf4* __restrict__ in4 = (const vf4*)inputs;
    vf4*       __restrict__ o4  = (vf4*)out;

    float ivl = 0.0f, ease = 0.0f;

    auto upd = [&](float delta_t, float rating) {
        const bool is_first = (ivl == 0.0f) || (ease == 0.0f);

        float ne = ease;
        ne = (rating == 1.0f) ? ease - 0.2f  : ne;
        ne = (rating == 2.0f) ? ease - 0.15f : ne;
        ne = (rating == 4.0f) ? ease + 0.15f : ne;
        ne = fminf(fmaxf(ne, 1.3f), 5.5f);

        const float days_late = delta_t - ivl;
        const bool pass_cond  = rating > 1.0f;
        const bool early      = pass_cond && (days_late <  0.0f);
        const bool non_early  = pass_cond && (days_late >= 0.0f);

        const float elapsed = ivl + days_late;
        const float e_hard  = fmaxf(elapsed * w4, ivl * w4 * 0.5f);
        const float e_good  = ivl * ne;
        const float e_easy  = e_good * w3;
        const float ivl_early =
            (rating == 2.0f) ? e_hard : ((rating == 4.0f) ? e_easy : e_good);

        const float n_hard = ivl * w4;
        const float n_good = (ivl + days_late * 0.5f)  * ne;
        const float n_easy = (ivl + days_late * 0.25f) * ne * w3;
        const float ivl_non_early =
            (rating == 2.0f) ? n_hard : ((rating == 4.0f) ? n_easy : n_good);

        const float calc =
            (early ? ivl_early : (non_early ? ivl_non_early : 0.0f)) * w6;

        float new_ivl = pass_cond ? calc : ivl;
        new_ivl = (rating == 1.0f) ? ivl * w5 : new_ivl;
        new_ivl = (is_first && rating <  4.0f) ? w0 : new_ivl;
        new_ivl = (is_first && rating == 4.0f) ? w1 : new_ivl;
        ne      = is_first ? w2 : ne;
        new_ivl = fminf(fmaxf(new_ivl, S_MIN), S_MAX);

        ivl  = new_ivl;
        ease = ne;
    };

#define U8(M) M(0) M(1) M(2) M(3) M(4) M(5) M(6) M(7)

    // ---- Prologue: stage group 0 into LDS. ----
#define LD0(j) vf4 r##j = in4[(size_t)(2*(j) + srow) * B4 + cbase];
    U8(LD0)
#undef LD0
#define WR(j) *(vf4*)&in_lds[2*(j) + srow][slot * 4] = r##j;
    U8(WR)
    __syncthreads();

    const int ngroups = seq_len >> 4;
    for (int g = 0; g < ngroups; ++g) {
        const int t0 = g << 4;
        const bool more = (g + 1) < ngroups;

        // Issue next group's global loads (in flight during compute).
        if (more) {
#define RLD(j) r##j = in4[(size_t)(t0 + 16 + 2*(j) + srow) * B4 + cbase];
            U8(RLD)
#undef RLD
        }

        // Compute 16 serial steps from LDS; results into out_lds.
#pragma unroll
        for (int s = 0; s < 16; ++s) {
            const float2 x = *(const float2*)&in_lds[s][tid * 2];
            upd(x.x, x.y);
            *(float2*)&out_lds[s][tid * 2] = make_float2(ivl, ease);
        }
        __syncthreads();   // out_lds complete; in_lds reads done

        // Stage next group's input into LDS (waits on the loads above).
        if (more) {
            U8(WR)
        }

        // Drain out_lds to global as dwordx4.
#define ST(j) { vf4 o = *(const vf4*)&out_lds[2*(j) + srow][slot * 4]; \
                o4[(size_t)(t0 + 2*(j) + srow) * B4 + cbase] = o; }
        U8(ST)
#undef ST
        __syncthreads();   // out_lds reads done; in_lds visible for next iter
    }
#undef WR
#undef U8

    // Final state [batch][2].
    float2* fin2 = (float2*)out + (size_t)seq_len * batch;
    fin2[col] = make_float2(ivl, ease);
}

extern "C" void kernel_launch(void* const* d_in, const int* in_sizes, int n_in,
                              void* d_out, int out_size, void* d_ws, size_t ws_size,
                              hipStream_t stream) {
    const float* inputs = (const float*)d_in[0];
    const float* w      = (const float*)d_in[1];
    float* out          = (float*)d_out;

    const int seq_len = 512;
    const int batch   = in_sizes[0] / (seq_len * 2);  // 65536

    const int block = 128;                 // 2 waves; 512 blocks = 2 per CU
    const int grid  = batch / block;
    anki_scan<<<grid, block, 0, stream>>>(inputs, w, out, seq_len, batch);
}